// Round 6
// baseline (18118.585 us; speedup 1.0000x reference)
//
#include <hip/hip_runtime.h>

// Persistent-kernel Graves RNN, split-precision (bf16 hi/lo ~ fp32) recurrence.
// Round 5/6: 1-hop all-poll barrier; window's h1·Wwin GEMM fused into the h1
// producers (per-block partials + f32 atomics into double-buffered wacc);
// chars staged in window-block LDS once. Window path off the critical chain.
// Blocks [0,128): GEMM (4 h-cols, both LSTMs). [128,192): window (1 batch row).

typedef unsigned int u32;
typedef unsigned short u16;
typedef unsigned long long u64;
typedef short short8 __attribute__((ext_vector_type(8)));
typedef float floatx4 __attribute__((ext_vector_type(4)));
typedef u32 u32x4 __attribute__((ext_vector_type(4)));

#define NBLK   192
#define NGEMM  128
#define NTHR   256
#define SLEN   600

// workspace layout (bytes)
#define OFF_FLAG 0ull                          // u32 flags[192] dense
#define OFF_WACC 1024ull                       // f32 wacc[2][64][60]
#define OFF_H1P  32768ull                      // u32[64*512] packed (hi | lo<<16)
#define OFF_H2P  (OFF_H1P + 131072ull)
#define OFF_WP   (OFF_H2P + 131072ull)         // u32[64*96] packed (cols 80..95 zero)
#define OFF_XHI  (OFF_WP + 24576ull)           // u16[600*64*32]
#define OFF_XLO  (OFF_XHI + 2457600ull)
#define OFF_HS2  (OFF_XLO + 2457600ull)        // u16[64*600*512] (plain cached)
#define WS_NEED  (OFF_HS2 + 39321600ull)       // ~42.5 MB

__device__ __forceinline__ float bf2f(short h) {
  return __uint_as_float(((u32)(u16)h) << 16);
}
__device__ __forceinline__ u16 f2bf(float f) {          // RNE
  u32 u = __float_as_uint(f);
  u += 0x7fffu + ((u >> 16) & 1u);
  return (u16)(u >> 16);
}
__device__ __forceinline__ float fsig(float x) { return 1.0f / (1.0f + __expf(-x)); }
__device__ __forceinline__ float ftanh_(float x) { return 2.0f / (1.0f + __expf(-2.0f * x)) - 1.0f; }

__device__ __forceinline__ float lstm_point(floatx4 g, float& c) {
  float i  = fsig(g[0]);
  float f  = fsig(g[1]);
  float gg = ftanh_(g[2]);
  float o  = fsig(g[3]);
  c = f * c + i * gg;
  return o * ftanh_(c);
}

// pack v as (trunc-bf16 hi) | (RNE-bf16 of remainder << 16)
__device__ __forceinline__ u32 pack_split(float v) {
  u32 b = __float_as_uint(v);
  float rem = v - __uint_as_float(b & 0xffff0000u);
  return (b >> 16) | ((u32)f2bf(rem) << 16);
}

// coherent (agent-scope, L2-bypass) helpers
__device__ __forceinline__ void st_coh(u32* p, u32 v) {
  __hip_atomic_store(p, v, __ATOMIC_RELAXED, __HIP_MEMORY_SCOPE_AGENT);
}
__device__ __forceinline__ u32 ld_coh(const u32* p) {
  return __hip_atomic_load((u32*)p, __ATOMIC_RELAXED, __HIP_MEMORY_SCOPE_AGENT);
}
__device__ __forceinline__ void stf_coh(float* p, float v) {
  __hip_atomic_store(p, v, __ATOMIC_RELAXED, __HIP_MEMORY_SCOPE_AGENT);
}
__device__ __forceinline__ float ldf_coh(const float* p) {
  return __hip_atomic_load((float*)p, __ATOMIC_RELAXED, __HIP_MEMORY_SCOPE_AGENT);
}

// load 8 consecutive packed u32 (coherent), split into hi/lo bf16 short8
__device__ __forceinline__ void ld_pk8(const u32* p, short8& hi, short8& lo) {
  u64 d0 = __hip_atomic_load((u64*)(p + 0), __ATOMIC_RELAXED, __HIP_MEMORY_SCOPE_AGENT);
  u64 d1 = __hip_atomic_load((u64*)(p + 2), __ATOMIC_RELAXED, __HIP_MEMORY_SCOPE_AGENT);
  u64 d2 = __hip_atomic_load((u64*)(p + 4), __ATOMIC_RELAXED, __HIP_MEMORY_SCOPE_AGENT);
  u64 d3 = __hip_atomic_load((u64*)(p + 6), __ATOMIC_RELAXED, __HIP_MEMORY_SCOPE_AGENT);
  u32 a0 = (u32)d0, a1 = (u32)(d0 >> 32), a2 = (u32)d1, a3 = (u32)(d1 >> 32);
  u32 a4 = (u32)d2, a5 = (u32)(d2 >> 32), a6 = (u32)d3, a7 = (u32)(d3 >> 32);
  u32x4 h, l;
  h[0] = __builtin_amdgcn_perm(a1, a0, 0x05040100u); l[0] = __builtin_amdgcn_perm(a1, a0, 0x07060302u);
  h[1] = __builtin_amdgcn_perm(a3, a2, 0x05040100u); l[1] = __builtin_amdgcn_perm(a3, a2, 0x07060302u);
  h[2] = __builtin_amdgcn_perm(a5, a4, 0x05040100u); l[2] = __builtin_amdgcn_perm(a5, a4, 0x07060302u);
  h[3] = __builtin_amdgcn_perm(a7, a6, 0x05040100u); l[3] = __builtin_amdgcn_perm(a7, a6, 0x07060302u);
  hi = __builtin_bit_cast(short8, h);
  lo = __builtin_bit_cast(short8, l);
}

// ---- all-poll 1-hop barrier: every block polls all 192 flags itself ----
__device__ __forceinline__ void poll_all(u32* flags, u32 lgen) {
  if (threadIdx.x < 64) {
    const int ln = threadIdx.x;
    u32 sp = 0;
    for (;;) {
      u32 f0 = ld_coh(&flags[ln]);
      u32 f1 = ld_coh(&flags[64 + ln]);
      u32 f2 = ld_coh(&flags[128 + ln]);
      bool ok = (f0 >= lgen) && (f1 >= lgen) && (f2 >= lgen);
      if (__all(ok)) break;
      __builtin_amdgcn_s_sleep(1);
      if (++sp > (1u << 20)) break;   // safety valve: degrade, don't hang
    }
  }
}

// light barrier: no cache maintenance (mutable shared data uses coherent ops)
__device__ __forceinline__ void sync_light(u32* flags, u32& lgen) {
  asm volatile("s_waitcnt vmcnt(0) lgkmcnt(0)" ::: "memory");  // drain own stores/atomics
  __syncthreads();
  lgen++;
  if (threadIdx.x == 0) st_coh(&flags[blockIdx.x], lgen);
  poll_all(flags, lgen);
  __syncthreads();
  asm volatile("" ::: "memory");
}

// full barrier: with L2 writeback/invalidate (prologue + pre-epilogue only)
__device__ __forceinline__ void sync_full(u32* flags, u32& lgen) {
  __syncthreads();
  lgen++;
  if (threadIdx.x == 0) {
    __threadfence();                 // release: wb dirty L2 (xpad / hs2)
    st_coh(&flags[blockIdx.x], lgen);
  }
  poll_all(flags, lgen);
  if (threadIdx.x == 0) __threadfence();   // acquire: invalidate
  __syncthreads();
  asm volatile("" ::: "memory");
}

__global__ void init_ws(unsigned char* ws) {
  const int gtid = blockIdx.x * 256 + threadIdx.x;
  u32* flg = (u32*)(ws + OFF_FLAG);
  if (gtid < NBLK) flg[gtid] = 0u;
  float* wacc = (float*)(ws + OFF_WACC);
  for (int i = gtid; i < 2 * 64 * 60; i += 64 * 256) wacc[i] = 0.0f;
  u32* h2p = (u32*)(ws + OFF_H2P);
  for (int i = gtid; i < 64 * 512; i += 64 * 256) h2p[i] = 0u;   // h2_{-1}=0
  u32* wp = (u32*)(ws + OFF_WP);
  for (int i = gtid; i < 64 * 96; i += 64 * 256) wp[i] = 0u;     // w pad cols
}

__global__ __launch_bounds__(NTHR, 1) void rnn_kernel(
    const float* __restrict__ x, const float* __restrict__ chars,
    const float* __restrict__ Wih1, const float* __restrict__ Whh1,
    const float* __restrict__ bih1, const float* __restrict__ bhh1,
    const float* __restrict__ Wwin, const float* __restrict__ bwin,
    const float* __restrict__ Wih2, const float* __restrict__ Whh2,
    const float* __restrict__ bih2, const float* __restrict__ bhh2,
    const float* __restrict__ Wmdn, const float* __restrict__ bmdn,
    float* __restrict__ out, unsigned char* __restrict__ ws)
{
  const int bid = blockIdx.x;
  const int tid = threadIdx.x;
  const int wid = tid >> 6;
  const int lane = tid & 63;

  u32* flags = (u32*)(ws + OFF_FLAG);
  float* wacc = (float*)(ws + OFF_WACC);
  u32* h1p   = (u32*)(ws + OFF_H1P);
  u32* h2p   = (u32*)(ws + OFF_H2P);
  u32* wp    = (u32*)(ws + OFF_WP);
  u16* xhi   = (u16*)(ws + OFF_XHI);
  u16* xlo   = (u16*)(ws + OFF_XLO);
  u16* hs2   = (u16*)(ws + OFF_HS2);

  u32 lgen = 0;

  // LDS: GEMM: lo-A-frags 40KB + wwin slice + h1new staging.
  //      Window: chars 20.5KB + softmax scratch.  (sum ~66KB, 1 block/CU ok)
  __shared__ __align__(16) u16 lofrag_s[40 * 512];
  __shared__ __align__(16) float chars_s[64 * 80];
  __shared__ float wwin_s[60 * 4];     // Wwin[c][4*bid+j]
  __shared__ float h1new_s[64 * 4];    // phase-B h1 staging for pwout
  __shared__ float wout_s[64];
  __shared__ float phi_s[64];
  __shared__ float al_s[20], be_s[20], kp_s[20];

  // ---- prologue: split x into xhi/xlo [t][b][32] (plain stores; full barrier) ----
  for (int i = bid * NTHR + tid; i < SLEN * 64 * 32; i += NBLK * NTHR) {
    int t = i >> 11;
    int r = i & 2047;
    int bb = r >> 5, q = r & 31;
    float v = (q < 3) ? x[((size_t)bb * SLEN + t) * 3 + q] : 0.0f;
    u32 b = __float_as_uint(v);
    xhi[i] = (u16)(b >> 16);
    xlo[i] = f2bf(v - __uint_as_float(b & 0xffff0000u));
  }

  const bool isg = (bid < NGEMM);

  short8 af1h[20], af2h[20];     // hi A-fragments: K = [h 512 | w 96 | x 32]
  float bs1[4], bs2[4];
  float c1 = 0.0f, c2 = 0.0f;
  int b_row = 0, hc = 0;
  float bw = 0.0f;
  const int kg = (lane >> 4) * 8;

  if (isg) {
    b_row = 16 * wid + (lane & 15);
    hc = 4 * bid + (lane >> 4);
    const int ra = lane & 15;
    const int origA = (ra & 3) * 512 + 4 * bid + (ra >> 2);  // gate*512 + hcol
    #pragma unroll
    for (int ks = 0; ks < 20; ++ks) {
      short8 v1h, v1l, v2h, v2l;
      #pragma unroll
      for (int j = 0; j < 8; ++j) {
        int k = 32 * ks + kg + j;
        float a1 = 0.0f, a2 = 0.0f;
        if (k < 512) {
          a1 = Whh1[(size_t)origA * 512 + k];
          a2 = Whh2[(size_t)origA * 512 + k];
        } else if (k < 592) {             // window: Wih cols 3..82
          a1 = Wih1[(size_t)origA * 83 + 3 + (k - 512)];
          a2 = Wih2[(size_t)origA * 83 + 3 + (k - 512)];
        } else if (k >= 608 && k < 611) { // x: Wih cols 0..2
          a1 = Wih1[(size_t)origA * 83 + (k - 608)];
          a2 = Wih2[(size_t)origA * 83 + (k - 608)];
        }
        u32 b1 = __float_as_uint(a1), b2 = __float_as_uint(a2);
        v1h[j] = (short)(u16)(b1 >> 16);
        v2h[j] = (short)(u16)(b2 >> 16);
        v1l[j] = (short)f2bf(a1 - __uint_as_float(b1 & 0xffff0000u));
        v2l[j] = (short)f2bf(a2 - __uint_as_float(b2 & 0xffff0000u));
      }
      af1h[ks] = v1h; af2h[ks] = v2h;
      if (wid == 0) {
        *(short8*)(lofrag_s + ((0 * 20 + ks) << 9) + (lane << 3)) = v1l;
        *(short8*)(lofrag_s + ((1 * 20 + ks) << 9) + (lane << 3)) = v2l;
      }
    }
    #pragma unroll
    for (int r = 0; r < 4; ++r) {
      bs1[r] = bih1[r * 512 + hc] + bhh1[r * 512 + hc];
      bs2[r] = bih2[r * 512 + hc] + bhh2[r * 512 + hc];
    }
    // Wwin slice for pwout: [60 c][4 j]
    for (int i = tid; i < 240; i += NTHR) {
      int c = i >> 2, j = i & 3;
      wwin_s[i] = Wwin[(size_t)c * 512 + 4 * bid + j];
    }
  } else {
    // window block b: stage chars[b] into LDS once
    const int b = bid - NGEMM;
    for (int i = tid; i < 64 * 80; i += NTHR)
      chars_s[i] = chars[(size_t)b * 5120 + i];
    if (tid < 20) kp_s[tid] = 0.0f;
    if (tid < 60) bw = bwin[tid];
  }

  sync_full(flags, lgen);   // xpad visible, LDS ready

  // ---- phase 0 ("B(-1)"): h1_0 = lstm(b1 + x_0*Wx1); pwout -> wacc[0] ----
  if (isg) {
    floatx4 a = { bs1[0], bs1[1], bs1[2], bs1[3] };
    floatx4 b = {0.f,0.f,0.f,0.f}, c = {0.f,0.f,0.f,0.f};
    short8 xh = *(const short8*)(xhi + (size_t)b_row * 32 + kg);
    short8 xl = *(const short8*)(xlo + (size_t)b_row * 32 + kg);
    short8 wl = *(const short8*)(lofrag_s + ((0 * 20 + 19) << 9) + (lane << 3));
    a = __builtin_amdgcn_mfma_f32_16x16x32_bf16(af1h[19], xh, a, 0, 0, 0);
    b = __builtin_amdgcn_mfma_f32_16x16x32_bf16(af1h[19], xl, b, 0, 0, 0);
    c = __builtin_amdgcn_mfma_f32_16x16x32_bf16(wl,       xh, c, 0, 0, 0);
    float h = lstm_point(a + b + c, c1);
    st_coh(&h1p[b_row * 512 + hc], pack_split(h));
    h1new_s[b_row * 4 + (lane >> 4)] = h;
    __syncthreads();
    for (int i = tid; i < 3840; i += NTHR) {
      int b2_ = i / 60, c2_ = i - 60 * b2_;
      float v = h1new_s[b2_ * 4 + 0] * wwin_s[c2_ * 4 + 0]
              + h1new_s[b2_ * 4 + 1] * wwin_s[c2_ * 4 + 1]
              + h1new_s[b2_ * 4 + 2] * wwin_s[c2_ * 4 + 2]
              + h1new_s[b2_ * 4 + 3] * wwin_s[c2_ * 4 + 3];
      atomicAdd(&wacc[0 * 3840 + i], v);
    }
  }

  sync_light(flags, lgen);   // h1_0, wacc[0] visible

  // ---- main loop ----
  for (int t = 0; t < SLEN; ++t) {
    floatx4 a1a = {0.f,0.f,0.f,0.f}, a1b = a1a, a1c = a1a;
    floatx4 a2a = {0.f,0.f,0.f,0.f}, a2b = a2a, a2c = a2a;

    // ======== phase A ========
    if (isg) {
      // partial gates2(t) = b2 + h2(t-1)*Whh2 + x(t)*Wx2
      a2a[0] = bs2[0]; a2a[1] = bs2[1]; a2a[2] = bs2[2]; a2a[3] = bs2[3];
      #pragma unroll
      for (int ks = 0; ks < 16; ++ks) {
        short8 bh, bl;
        ld_pk8(h2p + b_row * 512 + ks * 32 + kg, bh, bl);
        short8 al = *(const short8*)(lofrag_s + ((20 + ks) << 9) + (lane << 3));
        a2a = __builtin_amdgcn_mfma_f32_16x16x32_bf16(af2h[ks], bh, a2a, 0, 0, 0);
        a2b = __builtin_amdgcn_mfma_f32_16x16x32_bf16(af2h[ks], bl, a2b, 0, 0, 0);
        a2c = __builtin_amdgcn_mfma_f32_16x16x32_bf16(al,       bh, a2c, 0, 0, 0);
      }
      {
        short8 xh = *(const short8*)(xhi + ((size_t)t * 64 + b_row) * 32 + kg);
        short8 xl = *(const short8*)(xlo + ((size_t)t * 64 + b_row) * 32 + kg);
        short8 al = *(const short8*)(lofrag_s + ((20 + 19) << 9) + (lane << 3));
        a2a = __builtin_amdgcn_mfma_f32_16x16x32_bf16(af2h[19], xh, a2a, 0, 0, 0);
        a2b = __builtin_amdgcn_mfma_f32_16x16x32_bf16(af2h[19], xl, a2b, 0, 0, 0);
        a2c = __builtin_amdgcn_mfma_f32_16x16x32_bf16(al,       xh, a2c, 0, 0, 0);
      }
      // partial gates1(t+1) = b1 + h1(t)*Whh1 + x(t+1)*Wx1
      if (t < SLEN - 1) {
        a1a[0] = bs1[0]; a1a[1] = bs1[1]; a1a[2] = bs1[2]; a1a[3] = bs1[3];
        #pragma unroll
        for (int ks = 0; ks < 16; ++ks) {
          short8 bh, bl;
          ld_pk8(h1p + b_row * 512 + ks * 32 + kg, bh, bl);
          short8 al = *(const short8*)(lofrag_s + (ks << 9) + (lane << 3));
          a1a = __builtin_amdgcn_mfma_f32_16x16x32_bf16(af1h[ks], bh, a1a, 0, 0, 0);
          a1b = __builtin_amdgcn_mfma_f32_16x16x32_bf16(af1h[ks], bl, a1b, 0, 0, 0);
          a1c = __builtin_amdgcn_mfma_f32_16x16x32_bf16(al,       bh, a1c, 0, 0, 0);
        }
        short8 xh = *(const short8*)(xhi + ((size_t)(t + 1) * 64 + b_row) * 32 + kg);
        short8 xl = *(const short8*)(xlo + ((size_t)(t + 1) * 64 + b_row) * 32 + kg);
        short8 al = *(const short8*)(lofrag_s + (19 << 9) + (lane << 3));
        a1a = __builtin_amdgcn_mfma_f32_16x16x32_bf16(af1h[19], xh, a1a, 0, 0, 0);
        a1b = __builtin_amdgcn_mfma_f32_16x16x32_bf16(af1h[19], xl, a1b, 0, 0, 0);
        a1c = __builtin_amdgcn_mfma_f32_16x16x32_bf16(al,       xh, a1c, 0, 0, 0);
      }
    } else {
      // ---- window block b: w(t) from wacc[t&1][b] + kappa + chars LDS ----
      const int b = bid - NGEMM;
      float* wa = wacc + (size_t)(t & 1) * 3840 + b * 60;
      if (tid < 60) {
        float v = ldf_coh(&wa[tid]);
        stf_coh(&wa[tid], 0.0f);        // zero-after-read (next use: B(t+1))
        wout_s[tid] = v + bw;
      }
      __syncthreads();
      if (tid < 20) {
        al_s[tid] = __expf(wout_s[tid]);
        be_s[tid] = __expf(wout_s[20 + tid]);
        kp_s[tid] += __expf(wout_s[40 + tid]);
      }
      __syncthreads();
      if (tid < 64) {
        float u = (float)tid;
        float ph = 0.0f;
        #pragma unroll
        for (int k = 0; k < 20; ++k) {
          float d = kp_s[k] - u;
          ph = fmaf(al_s[k], __expf(-be_s[k] * d * d), ph);
        }
        phi_s[tid] = ph;
      }
      __syncthreads();
      if (tid < 80) {
        float wv = 0.0f;
        for (int u = 0; u < 64; ++u)
          wv = fmaf(phi_s[u], chars_s[u * 80 + tid], wv);
        st_coh(&wp[b * 96 + tid], pack_split(wv));
      }
    }

    sync_light(flags, lgen);   // w(t) visible; S1 partials done

    // ======== phase B ========
    if (isg) {
      short8 wh0, wl0, wh1, wl1, wh2, wl2;
      ld_pk8(wp + b_row * 96 +  0 + kg, wh0, wl0);
      ld_pk8(wp + b_row * 96 + 32 + kg, wh1, wl1);
      ld_pk8(wp + b_row * 96 + 64 + kg, wh2, wl2);
      short8 al0 = *(const short8*)(lofrag_s + ((20 + 16) << 9) + (lane << 3));
      short8 al1 = *(const short8*)(lofrag_s + ((20 + 17) << 9) + (lane << 3));
      short8 al2 = *(const short8*)(lofrag_s + ((20 + 18) << 9) + (lane << 3));
      a2a = __builtin_amdgcn_mfma_f32_16x16x32_bf16(af2h[16], wh0, a2a, 0, 0, 0);
      a2b = __builtin_amdgcn_mfma_f32_16x16x32_bf16(af2h[16], wl0, a2b, 0, 0, 0);
      a2c = __builtin_amdgcn_mfma_f32_16x16x32_bf16(al0,      wh0, a2c, 0, 0, 0);
      a2a = __builtin_amdgcn_mfma_f32_16x16x32_bf16(af2h[17], wh1, a2a, 0, 0, 0);
      a2b = __builtin_amdgcn_mfma_f32_16x16x32_bf16(af2h[17], wl1, a2b, 0, 0, 0);
      a2c = __builtin_amdgcn_mfma_f32_16x16x32_bf16(al1,      wh1, a2c, 0, 0, 0);
      a2a = __builtin_amdgcn_mfma_f32_16x16x32_bf16(af2h[18], wh2, a2a, 0, 0, 0);
      a2b = __builtin_amdgcn_mfma_f32_16x16x32_bf16(af2h[18], wl2, a2b, 0, 0, 0);
      a2c = __builtin_amdgcn_mfma_f32_16x16x32_bf16(al2,      wh2, a2c, 0, 0, 0);
      float h2v = lstm_point(a2a + a2b + a2c, c2);
      st_coh(&h2p[b_row * 512 + hc], pack_split(h2v));
      hs2[((size_t)b_row * SLEN + t) * 512 + hc] = f2bf(h2v);   // plain cached
      if (t < SLEN - 1) {
        short8 bl0 = *(const short8*)(lofrag_s + (16 << 9) + (lane << 3));
        short8 bl1 = *(const short8*)(lofrag_s + (17 << 9) + (lane << 3));
        short8 bl2 = *(const short8*)(lofrag_s + (18 << 9) + (lane << 3));
        a1a = __builtin_amdgcn_mfma_f32_16x16x32_bf16(af1h[16], wh0, a1a, 0, 0, 0);
        a1b = __builtin_amdgcn_mfma_f32_16x16x32_bf16(af1h[16], wl0, a1b, 0, 0, 0);
        a1c = __builtin_amdgcn_mfma_f32_16x16x32_bf16(bl0,      wh0, a1c, 0, 0, 0);
        a1a = __builtin_amdgcn_mfma_f32_16x16x32_bf16(af1h[17], wh1, a1a, 0, 0, 0);
        a1b = __builtin_amdgcn_mfma_f32_16x16x32_bf16(af1h[17], wl1, a1b, 0, 0, 0);
        a1c = __builtin_amdgcn_mfma_f32_16x16x32_bf16(bl1,      wh1, a1c, 0, 0, 0);
        a1a = __builtin_amdgcn_mfma_f32_16x16x32_bf16(af1h[18], wh2, a1a, 0, 0, 0);
        a1b = __builtin_amdgcn_mfma_f32_16x16x32_bf16(af1h[18], wl2, a1b, 0, 0, 0);
        a1c = __builtin_amdgcn_mfma_f32_16x16x32_bf16(bl2,      wh2, a1c, 0, 0, 0);
        float h1v = lstm_point(a1a + a1b + a1c, c1);
        st_coh(&h1p[b_row * 512 + hc], pack_split(h1v));
        h1new_s[b_row * 4 + (lane >> 4)] = h1v;
        __syncthreads();
        // pwout partials -> wacc[(t+1)&1]
        float* wa = wacc + (size_t)((t + 1) & 1) * 3840;
        for (int i = tid; i < 3840; i += NTHR) {
          int b2_ = i / 60, c2_ = i - 60 * b2_;
          float v = h1new_s[b2_ * 4 + 0] * wwin_s[c2_ * 4 + 0]
                  + h1new_s[b2_ * 4 + 1] * wwin_s[c2_ * 4 + 1]
                  + h1new_s[b2_ * 4 + 2] * wwin_s[c2_ * 4 + 2]
                  + h1new_s[b2_ * 4 + 3] * wwin_s[c2_ * 4 + 3];
          atomicAdd(&wa[i], v);
        }
      }
    }

    sync_light(flags, lgen);   // h1(t+1), h2(t), wacc(t+1) visible
  }

  sync_full(flags, lgen);   // flush hs2 to L3 before epilogue

  // ---- epilogue: MDN head, one row per thread ----
  {
    const int row = bid * NTHR + tid;          // row = b*600 + t
    if (row < 38400) {
      const u16* hrow = hs2 + (size_t)row * 512;
      {
        float acc = bmdn[0];
        for (int k8 = 0; k8 < 512; k8 += 8) {
          short8 hv = *(const short8*)(hrow + k8);
          #pragma unroll
          for (int j = 0; j < 8; ++j) acc = fmaf(bf2f(hv[j]), Wmdn[k8 + j], acc);
        }
        out[row] = fsig(acc);
      }
      {
        float a[20];
        #pragma unroll
        for (int cc = 0; cc < 20; ++cc) a[cc] = bmdn[1 + cc];
        for (int k8 = 0; k8 < 512; k8 += 8) {
          short8 hv = *(const short8*)(hrow + k8);
          float hf[8];
          #pragma unroll
          for (int j = 0; j < 8; ++j) hf[j] = bf2f(hv[j]);
          #pragma unroll
          for (int cc = 0; cc < 20; ++cc) {
            const float* wr = Wmdn + (size_t)(1 + cc) * 512 + k8;
            #pragma unroll
            for (int j = 0; j < 8; ++j) a[cc] = fmaf(hf[j], wr[j], a[cc]);
          }
        }
        float mx = a[0];
        #pragma unroll
        for (int cc = 1; cc < 20; ++cc) mx = fmaxf(mx, a[cc]);
        float s = 0.0f;
        #pragma unroll
        for (int cc = 0; cc < 20; ++cc) { a[cc] = __expf(a[cc] - mx); s += a[cc]; }
        float inv = 1.0f / s;
        float* po = out + 38400 + (size_t)row * 20;
        #pragma unroll
        for (int cc = 0; cc < 20; ++cc) po[cc] = a[cc] * inv;
      }
      for (int grp = 1; grp <= 5; ++grp) {
        float a[20];
        #pragma unroll
        for (int cc = 0; cc < 20; ++cc) a[cc] = bmdn[1 + 20 * grp + cc];
        for (int k8 = 0; k8 < 512; k8 += 8) {
          short8 hv = *(const short8*)(hrow + k8);
          float hf[8];
          #pragma unroll
          for (int j = 0; j < 8; ++j) hf[j] = bf2f(hv[j]);
          #pragma unroll
          for (int cc = 0; cc < 20; ++cc) {
            const float* wr = Wmdn + (size_t)(1 + 20 * grp + cc) * 512 + k8;
            #pragma unroll
            for (int j = 0; j < 8; ++j) a[cc] = fmaf(hf[j], wr[j], a[cc]);
          }
        }
        float* po = out + 38400 + (size_t)grp * 768000 + (size_t)row * 20;
        if (grp == 3 || grp == 4) {
          #pragma unroll
          for (int cc = 0; cc < 20; ++cc) po[cc] = __expf(a[cc]);
        } else if (grp == 5) {
          #pragma unroll
          for (int cc = 0; cc < 20; ++cc) po[cc] = ftanh_(a[cc]);
        } else {
          #pragma unroll
          for (int cc = 0; cc < 20; ++cc) po[cc] = a[cc];
        }
      }
    }
  }
}

extern "C" void kernel_launch(void* const* d_in, const int* in_sizes, int n_in,
                              void* d_out, int out_size, void* d_ws, size_t ws_size,
                              hipStream_t stream) {
  (void)in_sizes; (void)n_in; (void)out_size;
  if (ws_size < WS_NEED) return;   // need ~42.5 MB scratch
  init_ws<<<dim3(64), dim3(256), 0, stream>>>((unsigned char*)d_ws);
  rnn_kernel<<<dim3(NBLK), dim3(NTHR), 0, stream>>>(
      (const float*)d_in[0],  (const float*)d_in[1],
      (const float*)d_in[2],  (const float*)d_in[3],
      (const float*)d_in[4],  (const float*)d_in[5],
      (const float*)d_in[6],  (const float*)d_in[7],
      (const float*)d_in[8],  (const float*)d_in[9],
      (const float*)d_in[10], (const float*)d_in[11],
      (const float*)d_in[12], (const float*)d_in[13],
      (float*)d_out, (unsigned char*)d_ws);
}

// Round 7
// 12860.742 us; speedup vs baseline: 1.4088x; 1.4088x over previous
//
#include <hip/hip_runtime.h>

// Persistent-kernel Graves RNN, split-precision (bf16 hi/lo ~ fp32) recurrence.
// Round 7: revert round-6 regressions (wacc atomics, all-poll barrier).
// Key fix vs round 4: hi A-fragments moved from VGPRs (160!) to LDS, freeing
// registers so phase A's 128 L3-coherent h-loads can pipeline deeply
// (8-ks chunks of 32 in-flight u64 loads). A-frags are lane-indexed only,
// identical across waves -> one LDS copy serves all 4 waves.
// Blocks [0,128): GEMM (4 h-cols, both LSTMs). [128,192): window (1 batch row).
// Block 192: barrier aggregator.

typedef unsigned int u32;
typedef unsigned short u16;
typedef unsigned long long u64;
typedef short short8 __attribute__((ext_vector_type(8)));
typedef float floatx4 __attribute__((ext_vector_type(4)));
typedef u32 u32x4 __attribute__((ext_vector_type(4)));

#define NBLK   193
#define NGEMM  128
#define AGG_BID 192
#define NTHR   256
#define SLEN   600

// workspace layout (bytes)
#define OFF_FLAG 0ull                          // u32 flags[NBLK] stride 16 u32
#define OFF_GEN  16384ull                      // u32 gen[8] stride 16 u32
#define OFF_H1P  32768ull                      // u32[64*512] packed (hi | lo<<16)
#define OFF_H2P  (OFF_H1P + 131072ull)
#define OFF_WP   (OFF_H2P + 131072ull)         // u32[64*96] packed (cols 80..95 zero)
#define OFF_XHI  (OFF_WP + 24576ull)           // u16[600*64*32]
#define OFF_XLO  (OFF_XHI + 2457600ull)
#define OFF_HS2  (OFF_XLO + 2457600ull)        // u16[64*600*512] (plain cached)
#define WS_NEED  (OFF_HS2 + 39321600ull)       // ~44.6 MB

__device__ __forceinline__ float bf2f(short h) {
  return __uint_as_float(((u32)(u16)h) << 16);
}
__device__ __forceinline__ u16 f2bf(float f) {          // RNE
  u32 u = __float_as_uint(f);
  u += 0x7fffu + ((u >> 16) & 1u);
  return (u16)(u >> 16);
}
__device__ __forceinline__ float fsig(float x) { return 1.0f / (1.0f + __expf(-x)); }
__device__ __forceinline__ float ftanh_(float x) { return 2.0f / (1.0f + __expf(-2.0f * x)) - 1.0f; }

__device__ __forceinline__ float lstm_point(floatx4 g, float& c) {
  float i  = fsig(g[0]);
  float f  = fsig(g[1]);
  float gg = ftanh_(g[2]);
  float o  = fsig(g[3]);
  c = f * c + i * gg;
  return o * ftanh_(c);
}

// pack v as (trunc-bf16 hi) | (RNE-bf16 of remainder << 16)
__device__ __forceinline__ u32 pack_split(float v) {
  u32 b = __float_as_uint(v);
  float rem = v - __uint_as_float(b & 0xffff0000u);
  return (b >> 16) | ((u32)f2bf(rem) << 16);
}

// coherent (agent-scope, L2-bypass) helpers
__device__ __forceinline__ void st_coh(u32* p, u32 v) {
  __hip_atomic_store(p, v, __ATOMIC_RELAXED, __HIP_MEMORY_SCOPE_AGENT);
}
__device__ __forceinline__ u32 ld_coh(const u32* p) {
  return __hip_atomic_load((u32*)p, __ATOMIC_RELAXED, __HIP_MEMORY_SCOPE_AGENT);
}

// load 8 consecutive packed u32 (coherent), split into hi/lo bf16 short8
__device__ __forceinline__ void ld_pk8(const u32* p, short8& hi, short8& lo) {
  u64 d0 = __hip_atomic_load((u64*)(p + 0), __ATOMIC_RELAXED, __HIP_MEMORY_SCOPE_AGENT);
  u64 d1 = __hip_atomic_load((u64*)(p + 2), __ATOMIC_RELAXED, __HIP_MEMORY_SCOPE_AGENT);
  u64 d2 = __hip_atomic_load((u64*)(p + 4), __ATOMIC_RELAXED, __HIP_MEMORY_SCOPE_AGENT);
  u64 d3 = __hip_atomic_load((u64*)(p + 6), __ATOMIC_RELAXED, __HIP_MEMORY_SCOPE_AGENT);
  u32 a0 = (u32)d0, a1 = (u32)(d0 >> 32), a2 = (u32)d1, a3 = (u32)(d1 >> 32);
  u32 a4 = (u32)d2, a5 = (u32)(d2 >> 32), a6 = (u32)d3, a7 = (u32)(d3 >> 32);
  u32x4 h, l;
  h[0] = __builtin_amdgcn_perm(a1, a0, 0x05040100u); l[0] = __builtin_amdgcn_perm(a1, a0, 0x07060302u);
  h[1] = __builtin_amdgcn_perm(a3, a2, 0x05040100u); l[1] = __builtin_amdgcn_perm(a3, a2, 0x07060302u);
  h[2] = __builtin_amdgcn_perm(a5, a4, 0x05040100u); l[2] = __builtin_amdgcn_perm(a5, a4, 0x07060302u);
  h[3] = __builtin_amdgcn_perm(a7, a6, 0x05040100u); l[3] = __builtin_amdgcn_perm(a7, a6, 0x07060302u);
  hi = __builtin_bit_cast(short8, h);
  lo = __builtin_bit_cast(short8, l);
}

// ---- 2-hop aggregator barrier (round-4 proven protocol) ----
__device__ __forceinline__ void sync_wait(u32* flags, u32* gen, u32 lgen, int bid) {
  if (bid == AGG_BID) {
    const int i = threadIdx.x;
    if (i < NBLK) {
      u32 sp = 0;
      while (ld_coh(&flags[i * 16]) < lgen) {
        __builtin_amdgcn_s_sleep(1);
        if (++sp > (1u << 22)) break;   // safety valve
      }
    }
    __syncthreads();
    if (threadIdx.x < 8) st_coh(&gen[threadIdx.x * 16], lgen);
  } else {
    if (threadIdx.x == 0) {
      u32 sp = 0;
      while (ld_coh(&gen[(bid & 7) * 16]) < lgen) {
        __builtin_amdgcn_s_sleep(2);
        if (++sp > (1u << 22)) break;   // safety valve
      }
    }
  }
}

// light barrier: no cache maintenance (mutable shared data uses coherent ops)
__device__ __forceinline__ void sync_light(u32* flags, u32* gen, u32& lgen, int bid) {
  asm volatile("s_waitcnt vmcnt(0) lgkmcnt(0)" ::: "memory");  // drain own stores
  __syncthreads();
  lgen++;
  if (threadIdx.x == 0) st_coh(&flags[bid * 16], lgen);
  sync_wait(flags, gen, lgen, bid);
  __syncthreads();
  asm volatile("" ::: "memory");
}

// full barrier: with L2 writeback/invalidate (prologue + pre-epilogue only)
__device__ __forceinline__ void sync_full(u32* flags, u32* gen, u32& lgen, int bid) {
  __syncthreads();
  lgen++;
  if (threadIdx.x == 0) {
    __threadfence();                 // release: wb dirty L2 (xpad / hs2)
    st_coh(&flags[bid * 16], lgen);
  }
  sync_wait(flags, gen, lgen, bid);
  if (threadIdx.x == 0) __threadfence();   // acquire: invalidate
  __syncthreads();
  asm volatile("" ::: "memory");
}

__global__ void init_ws(unsigned char* ws) {
  const int gtid = blockIdx.x * 256 + threadIdx.x;
  u32* flg = (u32*)(ws + OFF_FLAG);
  for (int i = gtid; i < NBLK * 16; i += 64 * 256) flg[i] = 0u;
  u32* gn = (u32*)(ws + OFF_GEN);
  if (gtid < 128) gn[gtid] = 0u;
  u32* h2p = (u32*)(ws + OFF_H2P);
  for (int i = gtid; i < 64 * 512; i += 64 * 256) h2p[i] = 0u;   // h2_{-1}=0
  u32* wp = (u32*)(ws + OFF_WP);
  for (int i = gtid; i < 64 * 96; i += 64 * 256) wp[i] = 0u;     // w pad cols
}

__global__ __launch_bounds__(NTHR, 1) void rnn_kernel(
    const float* __restrict__ x, const float* __restrict__ chars,
    const float* __restrict__ Wih1, const float* __restrict__ Whh1,
    const float* __restrict__ bih1, const float* __restrict__ bhh1,
    const float* __restrict__ Wwin, const float* __restrict__ bwin,
    const float* __restrict__ Wih2, const float* __restrict__ Whh2,
    const float* __restrict__ bih2, const float* __restrict__ bhh2,
    const float* __restrict__ Wmdn, const float* __restrict__ bmdn,
    float* __restrict__ out, unsigned char* __restrict__ ws)
{
  const int bid = blockIdx.x;
  const int tid = threadIdx.x;
  const int wid = tid >> 6;
  const int lane = tid & 63;

  u32* flags = (u32*)(ws + OFF_FLAG);
  u32* gen   = (u32*)(ws + OFF_GEN);
  u32* h1p   = (u32*)(ws + OFF_H1P);
  u32* h2p   = (u32*)(ws + OFF_H2P);
  u32* wp    = (u32*)(ws + OFF_WP);
  u16* xhi   = (u16*)(ws + OFF_XHI);
  u16* xlo   = (u16*)(ws + OFF_XLO);
  u16* hs2   = (u16*)(ws + OFF_HS2);

  u32 lgen = 0;

  // LDS (~104 KB): hi+lo A-fragments (80 KB, GEMM) + chars (20.5 KB, window)
  // + window scratch. 1 block/CU.
  __shared__ __align__(16) u16 hifrag_s[40 * 512];   // (m*20+ks)*512 + lane*8
  __shared__ __align__(16) u16 lofrag_s[40 * 512];
  __shared__ __align__(16) float chars_s[64 * 80];
  __shared__ __align__(16) float smem_f[512];
  __shared__ float wout_s[64];
  __shared__ float al_s[20], be_s[20], kp_s[20];

  // ---- prologue: split x into xhi/xlo [t][b][32] (plain stores; full barrier) ----
  for (int i = bid * NTHR + tid; i < SLEN * 64 * 32; i += NBLK * NTHR) {
    int t = i >> 11;
    int r = i & 2047;
    int bb = r >> 5, q = r & 31;
    float v = (q < 3) ? x[((size_t)bb * SLEN + t) * 3 + q] : 0.0f;
    u32 b = __float_as_uint(v);
    xhi[i] = (u16)(b >> 16);
    xlo[i] = f2bf(v - __uint_as_float(b & 0xffff0000u));
  }

  const bool isg = (bid < NGEMM);
  const bool isw = (bid >= NGEMM && bid < NGEMM + 64);

  float bs1[4], bs2[4];
  float c1 = 0.0f, c2 = 0.0f;
  int b_row = 0, hc = 0;
  float bw = 0.0f;
  const int kg = (lane >> 4) * 8;

  if (isg) {
    b_row = 16 * wid + (lane & 15);
    hc = 4 * bid + (lane >> 4);
    // A-fragments -> LDS (wave 0 only; identical across waves)
    if (wid == 0) {
      const int ra = lane & 15;
      const int origA = (ra & 3) * 512 + 4 * bid + (ra >> 2);  // gate*512 + hcol
      #pragma unroll
      for (int ks = 0; ks < 20; ++ks) {
        short8 v1h, v1l, v2h, v2l;
        #pragma unroll
        for (int j = 0; j < 8; ++j) {
          int k = 32 * ks + kg + j;
          float a1 = 0.0f, a2 = 0.0f;
          if (k < 512) {
            a1 = Whh1[(size_t)origA * 512 + k];
            a2 = Whh2[(size_t)origA * 512 + k];
          } else if (k < 592) {             // window: Wih cols 3..82
            a1 = Wih1[(size_t)origA * 83 + 3 + (k - 512)];
            a2 = Wih2[(size_t)origA * 83 + 3 + (k - 512)];
          } else if (k >= 608 && k < 611) { // x: Wih cols 0..2
            a1 = Wih1[(size_t)origA * 83 + (k - 608)];
            a2 = Wih2[(size_t)origA * 83 + (k - 608)];
          }
          u32 b1 = __float_as_uint(a1), b2 = __float_as_uint(a2);
          v1h[j] = (short)(u16)(b1 >> 16);
          v2h[j] = (short)(u16)(b2 >> 16);
          v1l[j] = (short)f2bf(a1 - __uint_as_float(b1 & 0xffff0000u));
          v2l[j] = (short)f2bf(a2 - __uint_as_float(b2 & 0xffff0000u));
        }
        *(short8*)(hifrag_s + ((0 * 20 + ks) << 9) + (lane << 3)) = v1h;
        *(short8*)(hifrag_s + ((1 * 20 + ks) << 9) + (lane << 3)) = v2h;
        *(short8*)(lofrag_s + ((0 * 20 + ks) << 9) + (lane << 3)) = v1l;
        *(short8*)(lofrag_s + ((1 * 20 + ks) << 9) + (lane << 3)) = v2l;
      }
    }
    #pragma unroll
    for (int r = 0; r < 4; ++r) {
      bs1[r] = bih1[r * 512 + hc] + bhh1[r * 512 + hc];
      bs2[r] = bih2[r * 512 + hc] + bhh2[r * 512 + hc];
    }
  } else if (isw) {
    // window block b: stage chars[b] into LDS once
    const int b = bid - NGEMM;
    for (int i = tid; i < 64 * 80; i += NTHR)
      chars_s[i] = chars[(size_t)b * 5120 + i];
    if (tid < 20) kp_s[tid] = 0.0f;
    if (tid < 60) bw = bwin[tid];
  }

  sync_full(flags, gen, lgen, bid);   // xpad visible, LDS frags ready

  // ---- phase 0: h1_0 = lstm(b1 + x_0*Wx1) ----
  if (isg) {
    floatx4 a = { bs1[0], bs1[1], bs1[2], bs1[3] };
    floatx4 b = {0.f,0.f,0.f,0.f}, c = {0.f,0.f,0.f,0.f};
    short8 xh = *(const short8*)(xhi + (size_t)b_row * 32 + kg);
    short8 xl = *(const short8*)(xlo + (size_t)b_row * 32 + kg);
    short8 ah = *(const short8*)(hifrag_s + ((0 * 20 + 19) << 9) + (lane << 3));
    short8 al = *(const short8*)(lofrag_s + ((0 * 20 + 19) << 9) + (lane << 3));
    a = __builtin_amdgcn_mfma_f32_16x16x32_bf16(ah, xh, a, 0, 0, 0);
    b = __builtin_amdgcn_mfma_f32_16x16x32_bf16(ah, xl, b, 0, 0, 0);
    c = __builtin_amdgcn_mfma_f32_16x16x32_bf16(al, xh, c, 0, 0, 0);
    float h = lstm_point(a + b + c, c1);
    st_coh(&h1p[b_row * 512 + hc], pack_split(h));
  }

  sync_light(flags, gen, lgen, bid);   // h1_0 visible

  // ---- main loop ----
  for (int t = 0; t < SLEN; ++t) {
    floatx4 a1a = {0.f,0.f,0.f,0.f}, a1b = a1a, a1c = a1a;
    floatx4 a2a = {0.f,0.f,0.f,0.f}, a2b = a2a, a2c = a2a;

    // ======== phase A ========
    if (isg) {
      // partial gates2(t) = b2 + h2(t-1)*Whh2 + x(t)*Wx2
      a2a[0] = bs2[0]; a2a[1] = bs2[1]; a2a[2] = bs2[2]; a2a[3] = bs2[3];
      #pragma unroll
      for (int g = 0; g < 2; ++g) {
        short8 bh[8], bl[8];
        #pragma unroll
        for (int k = 0; k < 8; ++k)
          ld_pk8(h2p + b_row * 512 + (g * 8 + k) * 32 + kg, bh[k], bl[k]);
        #pragma unroll
        for (int k = 0; k < 8; ++k) {
          const int ks = g * 8 + k;
          short8 ah = *(const short8*)(hifrag_s + ((20 + ks) << 9) + (lane << 3));
          short8 al = *(const short8*)(lofrag_s + ((20 + ks) << 9) + (lane << 3));
          a2a = __builtin_amdgcn_mfma_f32_16x16x32_bf16(ah, bh[k], a2a, 0, 0, 0);
          a2b = __builtin_amdgcn_mfma_f32_16x16x32_bf16(ah, bl[k], a2b, 0, 0, 0);
          a2c = __builtin_amdgcn_mfma_f32_16x16x32_bf16(al, bh[k], a2c, 0, 0, 0);
        }
      }
      {
        short8 xh = *(const short8*)(xhi + ((size_t)t * 64 + b_row) * 32 + kg);
        short8 xl = *(const short8*)(xlo + ((size_t)t * 64 + b_row) * 32 + kg);
        short8 ah = *(const short8*)(hifrag_s + ((20 + 19) << 9) + (lane << 3));
        short8 al = *(const short8*)(lofrag_s + ((20 + 19) << 9) + (lane << 3));
        a2a = __builtin_amdgcn_mfma_f32_16x16x32_bf16(ah, xh, a2a, 0, 0, 0);
        a2b = __builtin_amdgcn_mfma_f32_16x16x32_bf16(ah, xl, a2b, 0, 0, 0);
        a2c = __builtin_amdgcn_mfma_f32_16x16x32_bf16(al, xh, a2c, 0, 0, 0);
      }
      // partial gates1(t+1) = b1 + h1(t)*Whh1 + x(t+1)*Wx1
      if (t < SLEN - 1) {
        a1a[0] = bs1[0]; a1a[1] = bs1[1]; a1a[2] = bs1[2]; a1a[3] = bs1[3];
        #pragma unroll
        for (int g = 0; g < 2; ++g) {
          short8 bh[8], bl[8];
          #pragma unroll
          for (int k = 0; k < 8; ++k)
            ld_pk8(h1p + b_row * 512 + (g * 8 + k) * 32 + kg, bh[k], bl[k]);
          #pragma unroll
          for (int k = 0; k < 8; ++k) {
            const int ks = g * 8 + k;
            short8 ah = *(const short8*)(hifrag_s + (ks << 9) + (lane << 3));
            short8 al = *(const short8*)(lofrag_s + (ks << 9) + (lane << 3));
            a1a = __builtin_amdgcn_mfma_f32_16x16x32_bf16(ah, bh[k], a1a, 0, 0, 0);
            a1b = __builtin_amdgcn_mfma_f32_16x16x32_bf16(ah, bl[k], a1b, 0, 0, 0);
            a1c = __builtin_amdgcn_mfma_f32_16x16x32_bf16(al, bh[k], a1c, 0, 0, 0);
          }
        }
        short8 xh = *(const short8*)(xhi + ((size_t)(t + 1) * 64 + b_row) * 32 + kg);
        short8 xl = *(const short8*)(xlo + ((size_t)(t + 1) * 64 + b_row) * 32 + kg);
        short8 ah = *(const short8*)(hifrag_s + (19 << 9) + (lane << 3));
        short8 al = *(const short8*)(lofrag_s + (19 << 9) + (lane << 3));
        a1a = __builtin_amdgcn_mfma_f32_16x16x32_bf16(ah, xh, a1a, 0, 0, 0);
        a1b = __builtin_amdgcn_mfma_f32_16x16x32_bf16(ah, xl, a1b, 0, 0, 0);
        a1c = __builtin_amdgcn_mfma_f32_16x16x32_bf16(al, xh, a1c, 0, 0, 0);
      }
    } else if (isw) {
      // ---- window block b: w(t) from h1(t), fp32 ----
      const int b = bid - NGEMM;
      for (int k = tid; k < 512; k += NTHR) {
        u32 p = ld_coh(&h1p[b * 512 + k]);
        smem_f[k] = bf2f((short)(u16)p) + bf2f((short)(u16)(p >> 16));
      }
      __syncthreads();
      const int col = tid & 63;
      const int kq  = tid >> 6;
      float p = 0.0f;
      if (col < 60) {
        const floatx4* wr = (const floatx4*)(Wwin + (size_t)col * 512 + kq * 128);
        const floatx4* hr = (const floatx4*)(smem_f + kq * 128);
        #pragma unroll
        for (int k4 = 0; k4 < 32; ++k4) {
          floatx4 wv = wr[k4];
          floatx4 hv = hr[k4];
          p = fmaf(wv[0], hv[0], p);
          p = fmaf(wv[1], hv[1], p);
          p = fmaf(wv[2], hv[2], p);
          p = fmaf(wv[3], hv[3], p);
        }
      }
      __syncthreads();              // done reading h (smem_f reused below)
      smem_f[tid] = p;
      __syncthreads();
      if (tid < 60)
        wout_s[tid] = smem_f[tid] + smem_f[64 + tid] + smem_f[128 + tid] + smem_f[192 + tid] + bw;
      __syncthreads();
      if (tid < 20) {
        al_s[tid] = __expf(wout_s[tid]);
        be_s[tid] = __expf(wout_s[20 + tid]);
        kp_s[tid] += __expf(wout_s[40 + tid]);
      }
      __syncthreads();
      if (tid < 64) {
        float u = (float)tid;
        float ph = 0.0f;
        #pragma unroll
        for (int k = 0; k < 20; ++k) {
          float d = kp_s[k] - u;
          ph = fmaf(al_s[k], __expf(-be_s[k] * d * d), ph);
        }
        smem_f[256 + tid] = ph;
      }
      __syncthreads();
      if (tid < 80) {
        float wv = 0.0f;
        for (int u = 0; u < 64; ++u)
          wv = fmaf(smem_f[256 + u], chars_s[u * 80 + tid], wv);
        st_coh(&wp[b * 96 + tid], pack_split(wv));
      }
    }

    sync_light(flags, gen, lgen, bid);   // w(t) visible; S1 partials done

    // ======== phase B ========
    if (isg) {
      short8 wh0, wl0, wh1, wl1, wh2, wl2;
      ld_pk8(wp + b_row * 96 +  0 + kg, wh0, wl0);
      ld_pk8(wp + b_row * 96 + 32 + kg, wh1, wl1);
      ld_pk8(wp + b_row * 96 + 64 + kg, wh2, wl2);
      short8 a2h0 = *(const short8*)(hifrag_s + ((20 + 16) << 9) + (lane << 3));
      short8 a2h1 = *(const short8*)(hifrag_s + ((20 + 17) << 9) + (lane << 3));
      short8 a2h2 = *(const short8*)(hifrag_s + ((20 + 18) << 9) + (lane << 3));
      short8 a2l0 = *(const short8*)(lofrag_s + ((20 + 16) << 9) + (lane << 3));
      short8 a2l1 = *(const short8*)(lofrag_s + ((20 + 17) << 9) + (lane << 3));
      short8 a2l2 = *(const short8*)(lofrag_s + ((20 + 18) << 9) + (lane << 3));
      a2a = __builtin_amdgcn_mfma_f32_16x16x32_bf16(a2h0, wh0, a2a, 0, 0, 0);
      a2b = __builtin_amdgcn_mfma_f32_16x16x32_bf16(a2h0, wl0, a2b, 0, 0, 0);
      a2c = __builtin_amdgcn_mfma_f32_16x16x32_bf16(a2l0, wh0, a2c, 0, 0, 0);
      a2a = __builtin_amdgcn_mfma_f32_16x16x32_bf16(a2h1, wh1, a2a, 0, 0, 0);
      a2b = __builtin_amdgcn_mfma_f32_16x16x32_bf16(a2h1, wl1, a2b, 0, 0, 0);
      a2c = __builtin_amdgcn_mfma_f32_16x16x32_bf16(a2l1, wh1, a2c, 0, 0, 0);
      a2a = __builtin_amdgcn_mfma_f32_16x16x32_bf16(a2h2, wh2, a2a, 0, 0, 0);
      a2b = __builtin_amdgcn_mfma_f32_16x16x32_bf16(a2h2, wl2, a2b, 0, 0, 0);
      a2c = __builtin_amdgcn_mfma_f32_16x16x32_bf16(a2l2, wh2, a2c, 0, 0, 0);
      float h2v = lstm_point(a2a + a2b + a2c, c2);
      st_coh(&h2p[b_row * 512 + hc], pack_split(h2v));
      hs2[((size_t)b_row * SLEN + t) * 512 + hc] = f2bf(h2v);   // plain cached
      if (t < SLEN - 1) {
        short8 a1h0 = *(const short8*)(hifrag_s + (16 << 9) + (lane << 3));
        short8 a1h1 = *(const short8*)(hifrag_s + (17 << 9) + (lane << 3));
        short8 a1h2 = *(const short8*)(hifrag_s + (18 << 9) + (lane << 3));
        short8 a1l0 = *(const short8*)(lofrag_s + (16 << 9) + (lane << 3));
        short8 a1l1 = *(const short8*)(lofrag_s + (17 << 9) + (lane << 3));
        short8 a1l2 = *(const short8*)(lofrag_s + (18 << 9) + (lane << 3));
        a1a = __builtin_amdgcn_mfma_f32_16x16x32_bf16(a1h0, wh0, a1a, 0, 0, 0);
        a1b = __builtin_amdgcn_mfma_f32_16x16x32_bf16(a1h0, wl0, a1b, 0, 0, 0);
        a1c = __builtin_amdgcn_mfma_f32_16x16x32_bf16(a1l0, wh0, a1c, 0, 0, 0);
        a1a = __builtin_amdgcn_mfma_f32_16x16x32_bf16(a1h1, wh1, a1a, 0, 0, 0);
        a1b = __builtin_amdgcn_mfma_f32_16x16x32_bf16(a1h1, wl1, a1b, 0, 0, 0);
        a1c = __builtin_amdgcn_mfma_f32_16x16x32_bf16(a1l1, wh1, a1c, 0, 0, 0);
        a1a = __builtin_amdgcn_mfma_f32_16x16x32_bf16(a1h2, wh2, a1a, 0, 0, 0);
        a1b = __builtin_amdgcn_mfma_f32_16x16x32_bf16(a1h2, wl2, a1b, 0, 0, 0);
        a1c = __builtin_amdgcn_mfma_f32_16x16x32_bf16(a1l2, wh2, a1c, 0, 0, 0);
        float h1v = lstm_point(a1a + a1b + a1c, c1);
        st_coh(&h1p[b_row * 512 + hc], pack_split(h1v));
      }
    }

    sync_light(flags, gen, lgen, bid);   // h1(t+1), h2(t) visible
  }

  sync_full(flags, gen, lgen, bid);   // flush hs2 to L3 before epilogue

  // ---- epilogue: MDN head, one row per thread ----
  {
    const int row = bid * NTHR + tid;          // row = b*600 + t
    if (row < 38400) {
      const u16* hrow = hs2 + (size_t)row * 512;
      {
        float acc = bmdn[0];
        for (int k8 = 0; k8 < 512; k8 += 8) {
          short8 hv = *(const short8*)(hrow + k8);
          #pragma unroll
          for (int j = 0; j < 8; ++j) acc = fmaf(bf2f(hv[j]), Wmdn[k8 + j], acc);
        }
        out[row] = fsig(acc);
      }
      {
        float a[20];
        #pragma unroll
        for (int cc = 0; cc < 20; ++cc) a[cc] = bmdn[1 + cc];
        for (int k8 = 0; k8 < 512; k8 += 8) {
          short8 hv = *(const short8*)(hrow + k8);
          float hf[8];
          #pragma unroll
          for (int j = 0; j < 8; ++j) hf[j] = bf2f(hv[j]);
          #pragma unroll
          for (int cc = 0; cc < 20; ++cc) {
            const float* wr = Wmdn + (size_t)(1 + cc) * 512 + k8;
            #pragma unroll
            for (int j = 0; j < 8; ++j) a[cc] = fmaf(hf[j], wr[j], a[cc]);
          }
        }
        float mx = a[0];
        #pragma unroll
        for (int cc = 1; cc < 20; ++cc) mx = fmaxf(mx, a[cc]);
        float s = 0.0f;
        #pragma unroll
        for (int cc = 0; cc < 20; ++cc) { a[cc] = __expf(a[cc] - mx); s += a[cc]; }
        float inv = 1.0f / s;
        float* po = out + 38400 + (size_t)row * 20;
        #pragma unroll
        for (int cc = 0; cc < 20; ++cc) po[cc] = a[cc] * inv;
      }
      for (int grp = 1; grp <= 5; ++grp) {
        float a[20];
        #pragma unroll
        for (int cc = 0; cc < 20; ++cc) a[cc] = bmdn[1 + 20 * grp + cc];
        for (int k8 = 0; k8 < 512; k8 += 8) {
          short8 hv = *(const short8*)(hrow + k8);
          float hf[8];
          #pragma unroll
          for (int j = 0; j < 8; ++j) hf[j] = bf2f(hv[j]);
          #pragma unroll
          for (int cc = 0; cc < 20; ++cc) {
            const float* wr = Wmdn + (size_t)(1 + 20 * grp + cc) * 512 + k8;
            #pragma unroll
            for (int j = 0; j < 8; ++j) a[cc] = fmaf(hf[j], wr[j], a[cc]);
          }
        }
        float* po = out + 38400 + (size_t)grp * 768000 + (size_t)row * 20;
        if (grp == 3 || grp == 4) {
          #pragma unroll
          for (int cc = 0; cc < 20; ++cc) po[cc] = __expf(a[cc]);
        } else if (grp == 5) {
          #pragma unroll
          for (int cc = 0; cc < 20; ++cc) po[cc] = ftanh_(a[cc]);
        } else {
          #pragma unroll
          for (int cc = 0; cc < 20; ++cc) po[cc] = a[cc];
        }
      }
    }
  }
}

extern "C" void kernel_launch(void* const* d_in, const int* in_sizes, int n_in,
                              void* d_out, int out_size, void* d_ws, size_t ws_size,
                              hipStream_t stream) {
  (void)in_sizes; (void)n_in; (void)out_size;
  if (ws_size < WS_NEED) return;   // need ~44.6 MB scratch
  init_ws<<<dim3(64), dim3(256), 0, stream>>>((unsigned char*)d_ws);
  rnn_kernel<<<dim3(NBLK), dim3(NTHR), 0, stream>>>(
      (const float*)d_in[0],  (const float*)d_in[1],
      (const float*)d_in[2],  (const float*)d_in[3],
      (const float*)d_in[4],  (const float*)d_in[5],
      (const float*)d_in[6],  (const float*)d_in[7],
      (const float*)d_in[8],  (const float*)d_in[9],
      (const float*)d_in[10], (const float*)d_in[11],
      (const float*)d_in[12], (const float*)d_in[13],
      (float*)d_out, (unsigned char*)d_ws);
}

// Round 8
// 12313.909 us; speedup vs baseline: 1.4714x; 1.0444x over previous
//
#include <hip/hip_runtime.h>

// Persistent-kernel Graves RNN, split-precision (bf16 hi/lo ~ fp32) recurrence.
// Round 8: occupancy fix — 512-thread blocks (8 waves = 2 waves/SIMD) so
// L3-bypass load latency overlaps across waves. GEMM blocks split K between
// wave-units (unit0: ks0-7 + x, partial -> LDS; unit1: ks8-15, + w + bias +
// pointwise + publish). Window blocks use 8 K-groups. Barrier protocol and
// numerics unchanged from round 7.
// Blocks [0,128): GEMM (4 h-cols, both LSTMs). [128,192): window (1 batch row).
// Block 192: barrier aggregator.

typedef unsigned int u32;
typedef unsigned short u16;
typedef unsigned long long u64;
typedef short short8 __attribute__((ext_vector_type(8)));
typedef float floatx4 __attribute__((ext_vector_type(4)));
typedef u32 u32x4 __attribute__((ext_vector_type(4)));

#define NBLK   193
#define NGEMM  128
#define AGG_BID 192
#define NTHR   512
#define SLEN   600

// workspace layout (bytes)
#define OFF_FLAG 0ull                          // u32 flags[NBLK] stride 16 u32
#define OFF_GEN  16384ull                      // u32 gen[8] stride 16 u32
#define OFF_H1P  32768ull                      // u32[64*512] packed (hi | lo<<16)
#define OFF_H2P  (OFF_H1P + 131072ull)
#define OFF_WP   (OFF_H2P + 131072ull)         // u32[64*96] packed (cols 80..95 zero)
#define OFF_XHI  (OFF_WP + 24576ull)           // u16[600*64*32]
#define OFF_XLO  (OFF_XHI + 2457600ull)
#define OFF_HS2  (OFF_XLO + 2457600ull)        // u16[64*600*512] (plain cached)
#define WS_NEED  (OFF_HS2 + 39321600ull)       // ~44.6 MB

__device__ __forceinline__ float bf2f(short h) {
  return __uint_as_float(((u32)(u16)h) << 16);
}
__device__ __forceinline__ u16 f2bf(float f) {          // RNE
  u32 u = __float_as_uint(f);
  u += 0x7fffu + ((u >> 16) & 1u);
  return (u16)(u >> 16);
}
__device__ __forceinline__ float fsig(float x) { return 1.0f / (1.0f + __expf(-x)); }
__device__ __forceinline__ float ftanh_(float x) { return 2.0f / (1.0f + __expf(-2.0f * x)) - 1.0f; }

__device__ __forceinline__ float lstm_point(floatx4 g, float& c) {
  float i  = fsig(g[0]);
  float f  = fsig(g[1]);
  float gg = ftanh_(g[2]);
  float o  = fsig(g[3]);
  c = f * c + i * gg;
  return o * ftanh_(c);
}

// pack v as (trunc-bf16 hi) | (RNE-bf16 of remainder << 16)
__device__ __forceinline__ u32 pack_split(float v) {
  u32 b = __float_as_uint(v);
  float rem = v - __uint_as_float(b & 0xffff0000u);
  return (b >> 16) | ((u32)f2bf(rem) << 16);
}

// coherent (agent-scope, L2-bypass) helpers
__device__ __forceinline__ void st_coh(u32* p, u32 v) {
  __hip_atomic_store(p, v, __ATOMIC_RELAXED, __HIP_MEMORY_SCOPE_AGENT);
}
__device__ __forceinline__ u32 ld_coh(const u32* p) {
  return __hip_atomic_load((u32*)p, __ATOMIC_RELAXED, __HIP_MEMORY_SCOPE_AGENT);
}

// load 8 consecutive packed u32 (coherent), split into hi/lo bf16 short8
__device__ __forceinline__ void ld_pk8(const u32* p, short8& hi, short8& lo) {
  u64 d0 = __hip_atomic_load((u64*)(p + 0), __ATOMIC_RELAXED, __HIP_MEMORY_SCOPE_AGENT);
  u64 d1 = __hip_atomic_load((u64*)(p + 2), __ATOMIC_RELAXED, __HIP_MEMORY_SCOPE_AGENT);
  u64 d2 = __hip_atomic_load((u64*)(p + 4), __ATOMIC_RELAXED, __HIP_MEMORY_SCOPE_AGENT);
  u64 d3 = __hip_atomic_load((u64*)(p + 6), __ATOMIC_RELAXED, __HIP_MEMORY_SCOPE_AGENT);
  u32 a0 = (u32)d0, a1 = (u32)(d0 >> 32), a2 = (u32)d1, a3 = (u32)(d1 >> 32);
  u32 a4 = (u32)d2, a5 = (u32)(d2 >> 32), a6 = (u32)d3, a7 = (u32)(d3 >> 32);
  u32x4 h, l;
  h[0] = __builtin_amdgcn_perm(a1, a0, 0x05040100u); l[0] = __builtin_amdgcn_perm(a1, a0, 0x07060302u);
  h[1] = __builtin_amdgcn_perm(a3, a2, 0x05040100u); l[1] = __builtin_amdgcn_perm(a3, a2, 0x07060302u);
  h[2] = __builtin_amdgcn_perm(a5, a4, 0x05040100u); l[2] = __builtin_amdgcn_perm(a5, a4, 0x07060302u);
  h[3] = __builtin_amdgcn_perm(a7, a6, 0x05040100u); l[3] = __builtin_amdgcn_perm(a7, a6, 0x07060302u);
  hi = __builtin_bit_cast(short8, h);
  lo = __builtin_bit_cast(short8, l);
}

// ---- 2-hop aggregator barrier (round-4 proven protocol) ----
__device__ __forceinline__ void sync_wait(u32* flags, u32* gen, u32 lgen, int bid) {
  if (bid == AGG_BID) {
    const int i = threadIdx.x;
    if (i < NBLK) {
      u32 sp = 0;
      while (ld_coh(&flags[i * 16]) < lgen) {
        __builtin_amdgcn_s_sleep(1);
        if (++sp > (1u << 22)) break;   // safety valve
      }
    }
    __syncthreads();
    if (threadIdx.x < 8) st_coh(&gen[threadIdx.x * 16], lgen);
  } else {
    if (threadIdx.x == 0) {
      u32 sp = 0;
      while (ld_coh(&gen[(bid & 7) * 16]) < lgen) {
        __builtin_amdgcn_s_sleep(2);
        if (++sp > (1u << 22)) break;   // safety valve
      }
    }
  }
}

// light barrier: no cache maintenance (mutable shared data uses coherent ops)
__device__ __forceinline__ void sync_light(u32* flags, u32* gen, u32& lgen, int bid) {
  asm volatile("s_waitcnt vmcnt(0) lgkmcnt(0)" ::: "memory");  // drain own stores
  __syncthreads();
  lgen++;
  if (threadIdx.x == 0) st_coh(&flags[bid * 16], lgen);
  sync_wait(flags, gen, lgen, bid);
  __syncthreads();
  asm volatile("" ::: "memory");
}

// full barrier: with L2 writeback/invalidate (prologue + pre-epilogue only)
__device__ __forceinline__ void sync_full(u32* flags, u32* gen, u32& lgen, int bid) {
  __syncthreads();
  lgen++;
  if (threadIdx.x == 0) {
    __threadfence();                 // release: wb dirty L2 (xpad / hs2)
    st_coh(&flags[bid * 16], lgen);
  }
  sync_wait(flags, gen, lgen, bid);
  if (threadIdx.x == 0) __threadfence();   // acquire: invalidate
  __syncthreads();
  asm volatile("" ::: "memory");
}

__global__ void init_ws(unsigned char* ws) {
  const int gtid = blockIdx.x * 256 + threadIdx.x;
  u32* flg = (u32*)(ws + OFF_FLAG);
  for (int i = gtid; i < NBLK * 16; i += 64 * 256) flg[i] = 0u;
  u32* gn = (u32*)(ws + OFF_GEN);
  if (gtid < 128) gn[gtid] = 0u;
  u32* h2p = (u32*)(ws + OFF_H2P);
  for (int i = gtid; i < 64 * 512; i += 64 * 256) h2p[i] = 0u;   // h2_{-1}=0
  u32* wp = (u32*)(ws + OFF_WP);
  for (int i = gtid; i < 64 * 96; i += 64 * 256) wp[i] = 0u;     // w pad cols
}

__global__ __launch_bounds__(NTHR, 1) void rnn_kernel(
    const float* __restrict__ x, const float* __restrict__ chars,
    const float* __restrict__ Wih1, const float* __restrict__ Whh1,
    const float* __restrict__ bih1, const float* __restrict__ bhh1,
    const float* __restrict__ Wwin, const float* __restrict__ bwin,
    const float* __restrict__ Wih2, const float* __restrict__ Whh2,
    const float* __restrict__ bih2, const float* __restrict__ bhh2,
    const float* __restrict__ Wmdn, const float* __restrict__ bmdn,
    float* __restrict__ out, unsigned char* __restrict__ ws)
{
  const int bid = blockIdx.x;
  const int tid = threadIdx.x;
  const int wid = tid >> 6;
  const int lane = tid & 63;
  const int unit = wid >> 2;        // 0: waves 0-3, 1: waves 4-7

  u32* flags = (u32*)(ws + OFF_FLAG);
  u32* gen   = (u32*)(ws + OFF_GEN);
  u32* h1p   = (u32*)(ws + OFF_H1P);
  u32* h2p   = (u32*)(ws + OFF_H2P);
  u32* wp    = (u32*)(ws + OFF_WP);
  u16* xhi   = (u16*)(ws + OFF_XHI);
  u16* xlo   = (u16*)(ws + OFF_XLO);
  u16* hs2   = (u16*)(ws + OFF_HS2);

  u32 lgen = 0;

  // LDS (~111 KB): hi+lo A-fragments (80 KB) + unit0 partials (8 KB) +
  // chars (20.5 KB, window) + scratch. 1 block/CU, 8 waves = 2/SIMD.
  __shared__ __align__(16) u16 hifrag_s[40 * 512];   // (m*20+ks)*512 + lane*8
  __shared__ __align__(16) u16 lofrag_s[40 * 512];
  __shared__ __align__(16) floatx4 plds[2][256];     // unit0 partial gates [m][tid]
  __shared__ __align__(16) float chars_s[64 * 80];
  __shared__ __align__(16) float smem_f[512];
  __shared__ float wout_s[64];
  __shared__ float al_s[20], be_s[20], kp_s[20];

  // ---- prologue: split x into xhi/xlo [t][b][32] (plain stores; full barrier) ----
  for (int i = bid * NTHR + tid; i < SLEN * 64 * 32; i += NBLK * NTHR) {
    int t = i >> 11;
    int r = i & 2047;
    int bb = r >> 5, q = r & 31;
    float v = (q < 3) ? x[((size_t)bb * SLEN + t) * 3 + q] : 0.0f;
    u32 b = __float_as_uint(v);
    xhi[i] = (u16)(b >> 16);
    xlo[i] = f2bf(v - __uint_as_float(b & 0xffff0000u));
  }

  const bool isg = (bid < NGEMM);
  const bool isw = (bid >= NGEMM && bid < NGEMM + 64);

  floatx4 bs1v = {0.f,0.f,0.f,0.f}, bs2v = bs1v;
  float c1 = 0.0f, c2 = 0.0f;
  int b_row = 0, hc = 0;
  float bw = 0.0f;
  const int kg = (lane >> 4) * 8;

  if (isg) {
    b_row = 16 * (wid & 3) + (lane & 15);
    hc = 4 * bid + (lane >> 4);
    // A-fragments -> LDS (wave 0 only; identical across waves)
    if (wid == 0) {
      const int ra = lane & 15;
      const int origA = (ra & 3) * 512 + 4 * bid + (ra >> 2);  // gate*512 + hcol
      #pragma unroll
      for (int ks = 0; ks < 20; ++ks) {
        short8 v1h, v1l, v2h, v2l;
        #pragma unroll
        for (int j = 0; j < 8; ++j) {
          int k = 32 * ks + kg + j;
          float a1 = 0.0f, a2 = 0.0f;
          if (k < 512) {
            a1 = Whh1[(size_t)origA * 512 + k];
            a2 = Whh2[(size_t)origA * 512 + k];
          } else if (k < 592) {             // window: Wih cols 3..82
            a1 = Wih1[(size_t)origA * 83 + 3 + (k - 512)];
            a2 = Wih2[(size_t)origA * 83 + 3 + (k - 512)];
          } else if (k >= 608 && k < 611) { // x: Wih cols 0..2
            a1 = Wih1[(size_t)origA * 83 + (k - 608)];
            a2 = Wih2[(size_t)origA * 83 + (k - 608)];
          }
          u32 b1 = __float_as_uint(a1), b2 = __float_as_uint(a2);
          v1h[j] = (short)(u16)(b1 >> 16);
          v2h[j] = (short)(u16)(b2 >> 16);
          v1l[j] = (short)f2bf(a1 - __uint_as_float(b1 & 0xffff0000u));
          v2l[j] = (short)f2bf(a2 - __uint_as_float(b2 & 0xffff0000u));
        }
        *(short8*)(hifrag_s + ((0 * 20 + ks) << 9) + (lane << 3)) = v1h;
        *(short8*)(hifrag_s + ((1 * 20 + ks) << 9) + (lane << 3)) = v2h;
        *(short8*)(lofrag_s + ((0 * 20 + ks) << 9) + (lane << 3)) = v1l;
        *(short8*)(lofrag_s + ((1 * 20 + ks) << 9) + (lane << 3)) = v2l;
      }
    }
    #pragma unroll
    for (int r = 0; r < 4; ++r) {
      bs1v[r] = bih1[r * 512 + hc] + bhh1[r * 512 + hc];
      bs2v[r] = bih2[r * 512 + hc] + bhh2[r * 512 + hc];
    }
  } else if (isw) {
    // window block b: stage chars[b] into LDS once
    const int b = bid - NGEMM;
    for (int i = tid; i < 64 * 80; i += NTHR)
      chars_s[i] = chars[(size_t)b * 5120 + i];
    if (tid < 20) kp_s[tid] = 0.0f;
    if (tid < 60) bw = bwin[tid];
  }

  sync_full(flags, gen, lgen, bid);   // xpad visible, LDS frags ready

  // ---- phase 0: h1_0 = lstm(b1 + x_0*Wx1); unit0 computes, unit1 publishes ----
  if (isg) {
    if (unit == 0) {
      floatx4 a = {0.f,0.f,0.f,0.f}, b = a, c = a;
      short8 xh = *(const short8*)(xhi + (size_t)b_row * 32 + kg);
      short8 xl = *(const short8*)(xlo + (size_t)b_row * 32 + kg);
      short8 ah = *(const short8*)(hifrag_s + (19 << 9) + (lane << 3));
      short8 al = *(const short8*)(lofrag_s + (19 << 9) + (lane << 3));
      a = __builtin_amdgcn_mfma_f32_16x16x32_bf16(ah, xh, a, 0, 0, 0);
      b = __builtin_amdgcn_mfma_f32_16x16x32_bf16(ah, xl, b, 0, 0, 0);
      c = __builtin_amdgcn_mfma_f32_16x16x32_bf16(al, xh, c, 0, 0, 0);
      plds[0][tid] = a + b + c;
    }
    __syncthreads();
    if (unit == 1) {
      floatx4 g = plds[0][tid - 256] + bs1v;
      float h = lstm_point(g, c1);
      st_coh(&h1p[b_row * 512 + hc], pack_split(h));
    }
  }

  sync_light(flags, gen, lgen, bid);   // h1_0 visible

  // ---- main loop ----
  for (int t = 0; t < SLEN; ++t) {
    floatx4 a1a = {0.f,0.f,0.f,0.f}, a1b = a1a, a1c = a1a;
    floatx4 a2a = {0.f,0.f,0.f,0.f}, a2b = a2a, a2c = a2a;

    // ======== phase A ========
    if (isg) {
      if (unit == 0) {
        // LSTM2 partial: h2 ks0-7 + x(t)
        {
          floatx4 pa = {0.f,0.f,0.f,0.f}, pb = pa, pc = pa;
          short8 bh[8], bl[8];
          #pragma unroll
          for (int k = 0; k < 8; ++k)
            ld_pk8(h2p + b_row * 512 + k * 32 + kg, bh[k], bl[k]);
          #pragma unroll
          for (int k = 0; k < 8; ++k) {
            short8 ah = *(const short8*)(hifrag_s + ((20 + k) << 9) + (lane << 3));
            short8 al = *(const short8*)(lofrag_s + ((20 + k) << 9) + (lane << 3));
            pa = __builtin_amdgcn_mfma_f32_16x16x32_bf16(ah, bh[k], pa, 0, 0, 0);
            pb = __builtin_amdgcn_mfma_f32_16x16x32_bf16(ah, bl[k], pb, 0, 0, 0);
            pc = __builtin_amdgcn_mfma_f32_16x16x32_bf16(al, bh[k], pc, 0, 0, 0);
          }
          short8 xh = *(const short8*)(xhi + ((size_t)t * 64 + b_row) * 32 + kg);
          short8 xl = *(const short8*)(xlo + ((size_t)t * 64 + b_row) * 32 + kg);
          short8 ah = *(const short8*)(hifrag_s + ((20 + 19) << 9) + (lane << 3));
          short8 al = *(const short8*)(lofrag_s + ((20 + 19) << 9) + (lane << 3));
          pa = __builtin_amdgcn_mfma_f32_16x16x32_bf16(ah, xh, pa, 0, 0, 0);
          pb = __builtin_amdgcn_mfma_f32_16x16x32_bf16(ah, xl, pb, 0, 0, 0);
          pc = __builtin_amdgcn_mfma_f32_16x16x32_bf16(al, xh, pc, 0, 0, 0);
          plds[1][tid] = pa + pb + pc;
        }
        // LSTM1 partial: h1 ks0-7 + x(t+1)
        if (t < SLEN - 1) {
          floatx4 pa = {0.f,0.f,0.f,0.f}, pb = pa, pc = pa;
          short8 bh[8], bl[8];
          #pragma unroll
          for (int k = 0; k < 8; ++k)
            ld_pk8(h1p + b_row * 512 + k * 32 + kg, bh[k], bl[k]);
          #pragma unroll
          for (int k = 0; k < 8; ++k) {
            short8 ah = *(const short8*)(hifrag_s + (k << 9) + (lane << 3));
            short8 al = *(const short8*)(lofrag_s + (k << 9) + (lane << 3));
            pa = __builtin_amdgcn_mfma_f32_16x16x32_bf16(ah, bh[k], pa, 0, 0, 0);
            pb = __builtin_amdgcn_mfma_f32_16x16x32_bf16(ah, bl[k], pb, 0, 0, 0);
            pc = __builtin_amdgcn_mfma_f32_16x16x32_bf16(al, bh[k], pc, 0, 0, 0);
          }
          short8 xh = *(const short8*)(xhi + ((size_t)(t + 1) * 64 + b_row) * 32 + kg);
          short8 xl = *(const short8*)(xlo + ((size_t)(t + 1) * 64 + b_row) * 32 + kg);
          short8 ah = *(const short8*)(hifrag_s + (19 << 9) + (lane << 3));
          short8 al = *(const short8*)(lofrag_s + (19 << 9) + (lane << 3));
          pa = __builtin_amdgcn_mfma_f32_16x16x32_bf16(ah, xh, pa, 0, 0, 0);
          pb = __builtin_amdgcn_mfma_f32_16x16x32_bf16(ah, xl, pb, 0, 0, 0);
          pc = __builtin_amdgcn_mfma_f32_16x16x32_bf16(al, xh, pc, 0, 0, 0);
          plds[0][tid] = pa + pb + pc;
        }
      } else {
        // unit 1: LSTM2 h2 ks8-15 (accumulators live into phase B)
        {
          short8 bh[8], bl[8];
          #pragma unroll
          for (int k = 0; k < 8; ++k)
            ld_pk8(h2p + b_row * 512 + (8 + k) * 32 + kg, bh[k], bl[k]);
          #pragma unroll
          for (int k = 0; k < 8; ++k) {
            short8 ah = *(const short8*)(hifrag_s + ((20 + 8 + k) << 9) + (lane << 3));
            short8 al = *(const short8*)(lofrag_s + ((20 + 8 + k) << 9) + (lane << 3));
            a2a = __builtin_amdgcn_mfma_f32_16x16x32_bf16(ah, bh[k], a2a, 0, 0, 0);
            a2b = __builtin_amdgcn_mfma_f32_16x16x32_bf16(ah, bl[k], a2b, 0, 0, 0);
            a2c = __builtin_amdgcn_mfma_f32_16x16x32_bf16(al, bh[k], a2c, 0, 0, 0);
          }
        }
        // LSTM1 h1 ks8-15
        if (t < SLEN - 1) {
          short8 bh[8], bl[8];
          #pragma unroll
          for (int k = 0; k < 8; ++k)
            ld_pk8(h1p + b_row * 512 + (8 + k) * 32 + kg, bh[k], bl[k]);
          #pragma unroll
          for (int k = 0; k < 8; ++k) {
            short8 ah = *(const short8*)(hifrag_s + ((8 + k) << 9) + (lane << 3));
            short8 al = *(const short8*)(lofrag_s + ((8 + k) << 9) + (lane << 3));
            a1a = __builtin_amdgcn_mfma_f32_16x16x32_bf16(ah, bh[k], a1a, 0, 0, 0);
            a1b = __builtin_amdgcn_mfma_f32_16x16x32_bf16(ah, bl[k], a1b, 0, 0, 0);
            a1c = __builtin_amdgcn_mfma_f32_16x16x32_bf16(al, bh[k], a1c, 0, 0, 0);
          }
        }
      }
    } else if (isw) {
      // ---- window block b: w(t) from h1(t), fp32, 8 K-groups ----
      const int b = bid - NGEMM;
      {
        u32 p = ld_coh(&h1p[b * 512 + tid]);
        smem_f[tid] = bf2f((short)(u16)p) + bf2f((short)(u16)(p >> 16));
      }
      __syncthreads();
      const int col = tid & 63;
      const int kq  = tid >> 6;          // 0..7, 64 K each
      float p = 0.0f;
      if (col < 60) {
        const floatx4* wr = (const floatx4*)(Wwin + (size_t)col * 512 + kq * 64);
        const floatx4* hr = (const floatx4*)(smem_f + kq * 64);
        #pragma unroll
        for (int k4 = 0; k4 < 16; ++k4) {
          floatx4 wv = wr[k4];
          floatx4 hv = hr[k4];
          p = fmaf(wv[0], hv[0], p);
          p = fmaf(wv[1], hv[1], p);
          p = fmaf(wv[2], hv[2], p);
          p = fmaf(wv[3], hv[3], p);
        }
      }
      __syncthreads();              // done reading h (smem_f reused below)
      smem_f[tid] = p;
      __syncthreads();
      if (tid < 60) {
        float s = 0.0f;
        #pragma unroll
        for (int q = 0; q < 8; ++q) s += smem_f[q * 64 + tid];
        wout_s[tid] = s + bw;
      }
      __syncthreads();
      if (tid < 20) {
        al_s[tid] = __expf(wout_s[tid]);
        be_s[tid] = __expf(wout_s[20 + tid]);
        kp_s[tid] += __expf(wout_s[40 + tid]);
      }
      __syncthreads();
      if (tid < 64) {
        float u = (float)tid;
        float ph = 0.0f;
        #pragma unroll
        for (int k = 0; k < 20; ++k) {
          float d = kp_s[k] - u;
          ph = fmaf(al_s[k], __expf(-be_s[k] * d * d), ph);
        }
        smem_f[tid] = ph;
      }
      __syncthreads();
      if (tid < 80) {
        float wv = 0.0f;
        for (int u = 0; u < 64; ++u)
          wv = fmaf(smem_f[u], chars_s[u * 80 + tid], wv);
        st_coh(&wp[b * 96 + tid], pack_split(wv));
      }
    }

    sync_light(flags, gen, lgen, bid);   // w(t) visible; unit0 partials in LDS

    // ======== phase B (unit 1 only) ========
    if (isg && unit == 1) {
      const int j = tid - 256;
      short8 wh0, wl0, wh1, wl1, wh2, wl2;
      ld_pk8(wp + b_row * 96 +  0 + kg, wh0, wl0);
      ld_pk8(wp + b_row * 96 + 32 + kg, wh1, wl1);
      ld_pk8(wp + b_row * 96 + 64 + kg, wh2, wl2);
      {
        short8 ah0 = *(const short8*)(hifrag_s + ((20 + 16) << 9) + (lane << 3));
        short8 ah1 = *(const short8*)(hifrag_s + ((20 + 17) << 9) + (lane << 3));
        short8 ah2 = *(const short8*)(hifrag_s + ((20 + 18) << 9) + (lane << 3));
        short8 al0 = *(const short8*)(lofrag_s + ((20 + 16) << 9) + (lane << 3));
        short8 al1 = *(const short8*)(lofrag_s + ((20 + 17) << 9) + (lane << 3));
        short8 al2 = *(const short8*)(lofrag_s + ((20 + 18) << 9) + (lane << 3));
        a2a = __builtin_amdgcn_mfma_f32_16x16x32_bf16(ah0, wh0, a2a, 0, 0, 0);
        a2b = __builtin_amdgcn_mfma_f32_16x16x32_bf16(ah0, wl0, a2b, 0, 0, 0);
        a2c = __builtin_amdgcn_mfma_f32_16x16x32_bf16(al0, wh0, a2c, 0, 0, 0);
        a2a = __builtin_amdgcn_mfma_f32_16x16x32_bf16(ah1, wh1, a2a, 0, 0, 0);
        a2b = __builtin_amdgcn_mfma_f32_16x16x32_bf16(ah1, wl1, a2b, 0, 0, 0);
        a2c = __builtin_amdgcn_mfma_f32_16x16x32_bf16(al1, wh1, a2c, 0, 0, 0);
        a2a = __builtin_amdgcn_mfma_f32_16x16x32_bf16(ah2, wh2, a2a, 0, 0, 0);
        a2b = __builtin_amdgcn_mfma_f32_16x16x32_bf16(ah2, wl2, a2b, 0, 0, 0);
        a2c = __builtin_amdgcn_mfma_f32_16x16x32_bf16(al2, wh2, a2c, 0, 0, 0);
      }
      floatx4 g2 = a2a + a2b + a2c + plds[1][j] + bs2v;
      float h2v = lstm_point(g2, c2);
      st_coh(&h2p[b_row * 512 + hc], pack_split(h2v));
      hs2[((size_t)b_row * SLEN + t) * 512 + hc] = f2bf(h2v);   // plain cached
      if (t < SLEN - 1) {
        short8 ah0 = *(const short8*)(hifrag_s + (16 << 9) + (lane << 3));
        short8 ah1 = *(const short8*)(hifrag_s + (17 << 9) + (lane << 3));
        short8 ah2 = *(const short8*)(hifrag_s + (18 << 9) + (lane << 3));
        short8 al0 = *(const short8*)(lofrag_s + (16 << 9) + (lane << 3));
        short8 al1 = *(const short8*)(lofrag_s + (17 << 9) + (lane << 3));
        short8 al2 = *(const short8*)(lofrag_s + (18 << 9) + (lane << 3));
        a1a = __builtin_amdgcn_mfma_f32_16x16x32_bf16(ah0, wh0, a1a, 0, 0, 0);
        a1b = __builtin_amdgcn_mfma_f32_16x16x32_bf16(ah0, wl0, a1b, 0, 0, 0);
        a1c = __builtin_amdgcn_mfma_f32_16x16x32_bf16(al0, wh0, a1c, 0, 0, 0);
        a1a = __builtin_amdgcn_mfma_f32_16x16x32_bf16(ah1, wh1, a1a, 0, 0, 0);
        a1b = __builtin_amdgcn_mfma_f32_16x16x32_bf16(ah1, wl1, a1b, 0, 0, 0);
        a1c = __builtin_amdgcn_mfma_f32_16x16x32_bf16(al1, wh1, a1c, 0, 0, 0);
        a1a = __builtin_amdgcn_mfma_f32_16x16x32_bf16(ah2, wh2, a1a, 0, 0, 0);
        a1b = __builtin_amdgcn_mfma_f32_16x16x32_bf16(ah2, wl2, a1b, 0, 0, 0);
        a1c = __builtin_amdgcn_mfma_f32_16x16x32_bf16(al2, wh2, a1c, 0, 0, 0);
        floatx4 g1 = a1a + a1b + a1c + plds[0][j] + bs1v;
        float h1v = lstm_point(g1, c1);
        st_coh(&h1p[b_row * 512 + hc], pack_split(h1v));
      }
    }

    sync_light(flags, gen, lgen, bid);   // h1(t+1), h2(t) visible
  }

  sync_full(flags, gen, lgen, bid);   // flush hs2 to L3 before epilogue

  // ---- epilogue: MDN head, one row per thread ----
  {
    const int row = bid * NTHR + tid;          // row = b*600 + t
    if (row < 38400) {
      const u16* hrow = hs2 + (size_t)row * 512;
      {
        float acc = bmdn[0];
        for (int k8 = 0; k8 < 512; k8 += 8) {
          short8 hv = *(const short8*)(hrow + k8);
          #pragma unroll
          for (int j = 0; j < 8; ++j) acc = fmaf(bf2f(hv[j]), Wmdn[k8 + j], acc);
        }
        out[row] = fsig(acc);
      }
      {
        float a[20];
        #pragma unroll
        for (int cc = 0; cc < 20; ++cc) a[cc] = bmdn[1 + cc];
        for (int k8 = 0; k8 < 512; k8 += 8) {
          short8 hv = *(const short8*)(hrow + k8);
          float hf[8];
          #pragma unroll
          for (int j = 0; j < 8; ++j) hf[j] = bf2f(hv[j]);
          #pragma unroll
          for (int cc = 0; cc < 20; ++cc) {
            const float* wr = Wmdn + (size_t)(1 + cc) * 512 + k8;
            #pragma unroll
            for (int j = 0; j < 8; ++j) a[cc] = fmaf(hf[j], wr[j], a[cc]);
          }
        }
        float mx = a[0];
        #pragma unroll
        for (int cc = 1; cc < 20; ++cc) mx = fmaxf(mx, a[cc]);
        float s = 0.0f;
        #pragma unroll
        for (int cc = 0; cc < 20; ++cc) { a[cc] = __expf(a[cc] - mx); s += a[cc]; }
        float inv = 1.0f / s;
        float* po = out + 38400 + (size_t)row * 20;
        #pragma unroll
        for (int cc = 0; cc < 20; ++cc) po[cc] = a[cc] * inv;
      }
      for (int grp = 1; grp <= 5; ++grp) {
        float a[20];
        #pragma unroll
        for (int cc = 0; cc < 20; ++cc) a[cc] = bmdn[1 + 20 * grp + cc];
        for (int k8 = 0; k8 < 512; k8 += 8) {
          short8 hv = *(const short8*)(hrow + k8);
          float hf[8];
          #pragma unroll
          for (int j = 0; j < 8; ++j) hf[j] = bf2f(hv[j]);
          #pragma unroll
          for (int cc = 0; cc < 20; ++cc) {
            const float* wr = Wmdn + (size_t)(1 + 20 * grp + cc) * 512 + k8;
            #pragma unroll
            for (int j = 0; j < 8; ++j) a[cc] = fmaf(hf[j], wr[j], a[cc]);
          }
        }
        float* po = out + 38400 + (size_t)grp * 768000 + (size_t)row * 20;
        if (grp == 3 || grp == 4) {
          #pragma unroll
          for (int cc = 0; cc < 20; ++cc) po[cc] = __expf(a[cc]);
        } else if (grp == 5) {
          #pragma unroll
          for (int cc = 0; cc < 20; ++cc) po[cc] = ftanh_(a[cc]);
        } else {
          #pragma unroll
          for (int cc = 0; cc < 20; ++cc) po[cc] = a[cc];
        }
      }
    }
  }
}

extern "C" void kernel_launch(void* const* d_in, const int* in_sizes, int n_in,
                              void* d_out, int out_size, void* d_ws, size_t ws_size,
                              hipStream_t stream) {
  (void)in_sizes; (void)n_in; (void)out_size;
  if (ws_size < WS_NEED) return;   // need ~44.6 MB scratch
  init_ws<<<dim3(64), dim3(256), 0, stream>>>((unsigned char*)d_ws);
  rnn_kernel<<<dim3(NBLK), dim3(NTHR), 0, stream>>>(
      (const float*)d_in[0],  (const float*)d_in[1],
      (const float*)d_in[2],  (const float*)d_in[3],
      (const float*)d_in[4],  (const float*)d_in[5],
      (const float*)d_in[6],  (const float*)d_in[7],
      (const float*)d_in[8],  (const float*)d_in[9],
      (const float*)d_in[10], (const float*)d_in[11],
      (const float*)d_in[12], (const float*)d_in[13],
      (float*)d_out, (unsigned char*)d_ws);
}